// Round 8
// baseline (160.522 us; speedup 1.0000x reference)
//
#include <hip/hip_runtime.h>

// BitDelta chained layers: per layer W = base + bd*mask (4096x4096 fp32),
// x = x @ W, x [16,4096].  Weight-streaming, memory-bound (~150 MB/layer).
//
// Stage 1 (per layer): grid 256 = (KCHUNKS=64) x (NCHUNKS=4), TPB=256
// (4 waves).  Block tile = 64 k-rows x 1024 cols; WAVES SPLIT COLUMNS
// (no inter-wave reduce).  Weights staged global->LDS via
// __builtin_amdgcn_global_load_lds (16 B/lane): each k-row is one 4 KB
// CONTIGUOUS cooperative load (4x the R7 granule), double-buffered
// (2 x 8 rows x 4 KB x 2 streams = 128 KB LDS), 16 fills in flight per
// wave = 64 KB/block >> 9 KB BDP.  x via wave-uniform scalar loads.
// Thread owns 4 cols: acc[16][4]; partial written directly (no atomics).
// Stage 2: 64-block kernel folds the 64 k-partials into the output.

#define DD 4096
#define BB 16
#define KC 64                  // k-rows per block
#define SS 8                   // k-rows per stage
#define NS (KC / SS)           // 8 stages
#define CT 1024                // cols per block
#define VEC 4
#define TPB 256                // 4 waves
#define KCHUNKS (DD / KC)      // 64
#define NCHUNKS (DD / CT)      // 4
#define OUT_ELEMS (BB * DD)    // 65536

typedef float f32x4 __attribute__((ext_vector_type(4)));

__device__ __forceinline__ void async_load16(const float* g, float* l) {
    __builtin_amdgcn_global_load_lds(
        (const __attribute__((address_space(1))) void*)g,
        (__attribute__((address_space(3))) void*)l, 16, 0, 0);
}

__global__ __launch_bounds__(TPB)
void bitdelta_layer(const float* __restrict__ x,
                    const float* __restrict__ base,
                    const float* __restrict__ mask,
                    const float* __restrict__ bitdelta,
                    int layer,
                    float* __restrict__ part) {
    __shared__ float bufB[2][SS][CT];   // 64 KB
    __shared__ float bufM[2][SS][CT];   // 64 KB

    const int tid = threadIdx.x;
    const int wid = __builtin_amdgcn_readfirstlane(tid >> 6);  // wave-uniform

    const int bid    = blockIdx.x;
    const int cchunk = bid & (NCHUNKS - 1);
    const int kchunk = bid >> 2;

    const int cblk = cchunk * CT;
    const int k0   = kchunk * KC;

    const float bd = bitdelta[layer];

    // Per-lane global base for staging (16 B per lane per row).
    const float* gB = base + (size_t)k0 * DD + cblk + tid * VEC;
    const float* gM = mask + (size_t)k0 * DD + cblk + tid * VEC;
    const int lds_off = wid * 256;      // wave-uniform float offset in a row

    float acc[BB][VEC];
#pragma unroll
    for (int r = 0; r < BB; ++r)
#pragma unroll
        for (int c = 0; c < VEC; ++c) acc[r][c] = 0.0f;

    // ---- stage fill: 16 async 16B/lane fills (8 rows x 2 streams) ----
    auto fill = [&](int bi, int stage) {
        const float* gb = gB + (size_t)stage * SS * DD;
        const float* gm = gM + (size_t)stage * SS * DD;
#pragma unroll
        for (int r = 0; r < SS; ++r) {
            async_load16(gb + (size_t)r * DD, &bufB[bi][r][lds_off]);
            async_load16(gm + (size_t)r * DD, &bufM[bi][r][lds_off]);
        }
    };

    // ---- stage compute: weights from LDS, x via scalar loads ----
    auto compute = [&](int bi, int stage) {
#pragma unroll
        for (int r = 0; r < SS; ++r) {
            const int k = k0 + stage * SS + r;
            const f32x4 b4 = *reinterpret_cast<const f32x4*>(&bufB[bi][r][tid * VEC]);
            const f32x4 m4 = *reinterpret_cast<const f32x4*>(&bufM[bi][r][tid * VEC]);
            const float w0 = fmaf(bd, m4[0], b4[0]);
            const float w1 = fmaf(bd, m4[1], b4[1]);
            const float w2 = fmaf(bd, m4[2], b4[2]);
            const float w3 = fmaf(bd, m4[3], b4[3]);
#pragma unroll
            for (int rr = 0; rr < BB; ++rr) {
                const float xv = x[(size_t)rr * DD + k];   // wave-uniform s_load
                acc[rr][0] = fmaf(xv, w0, acc[rr][0]);
                acc[rr][1] = fmaf(xv, w1, acc[rr][1]);
                acc[rr][2] = fmaf(xv, w2, acc[rr][2]);
                acc[rr][3] = fmaf(xv, w3, acc[rr][3]);
            }
        }
    };

    fill(0, 0);
    __syncthreads();                    // drain prologue fills
    for (int s = 0; s < NS; ++s) {
        if (s + 1 < NS) fill((s + 1) & 1, s + 1);
        compute(s & 1, s);
        __syncthreads();                // vmcnt(0) drain = next buffer ready
    }

    // Partial write: every thread owns its 4 cols (no reduce, no atomics).
    float* pp = part + (size_t)kchunk * OUT_ELEMS + cblk + tid * VEC;
#pragma unroll
    for (int rr = 0; rr < BB; ++rr) {
        f32x4 v = { acc[rr][0], acc[rr][1], acc[rr][2], acc[rr][3] };
        *reinterpret_cast<f32x4*>(pp + (size_t)rr * DD) = v;
    }
}

// Stage 2: out[e] = sum_k part[k][e].  64 blocks x 256 threads x float4.
__global__ __launch_bounds__(256)
void reduce_partials(const float* __restrict__ part, float* __restrict__ out) {
    const int idx = (blockIdx.x * 256 + threadIdx.x) * 4;
    f32x4 a = *reinterpret_cast<const f32x4*>(&part[idx]);
#pragma unroll
    for (int k = 1; k < KCHUNKS; ++k) {
        const f32x4 p = *reinterpret_cast<const f32x4*>(
            &part[(size_t)k * OUT_ELEMS + idx]);
        a += p;
    }
    *reinterpret_cast<f32x4*>(&out[idx]) = a;
}

extern "C" void kernel_launch(void* const* d_in, const int* in_sizes, int n_in,
                              void* d_out, int out_size, void* d_ws, size_t ws_size,
                              hipStream_t stream) {
    const float* x    = (const float*)d_in[0];   // [16,4096]
    const float* base = (const float*)d_in[1];   // [4,4096,4096]
    const float* mask = (const float*)d_in[2];   // [4,4096,4096]
    const float* bd   = (const float*)d_in[3];   // [4]
    float* out = (float*)d_out;                  // [16,4096] fp32

    float* part = (float*)d_ws;                  // 64 x 65536 floats = 16 MB
    float* y0   = part + (size_t)KCHUNKS * OUT_ELEMS;
    float* y1   = y0 + OUT_ELEMS;

    const size_t layer_stride = (size_t)DD * DD;
    const int    grid1 = KCHUNKS * NCHUNKS;      // 256
    const int    grid2 = OUT_ELEMS / (256 * 4);  // 64

    bitdelta_layer<<<grid1, TPB, 0, stream>>>(x, base, mask, bd, 0, part);
    reduce_partials<<<grid2, 256, 0, stream>>>(part, y0);

    bitdelta_layer<<<grid1, TPB, 0, stream>>>(y0, base + 1 * layer_stride,
                                              mask + 1 * layer_stride, bd, 1, part);
    reduce_partials<<<grid2, 256, 0, stream>>>(part, y1);

    bitdelta_layer<<<grid1, TPB, 0, stream>>>(y1, base + 2 * layer_stride,
                                              mask + 2 * layer_stride, bd, 2, part);
    reduce_partials<<<grid2, 256, 0, stream>>>(part, y0);

    bitdelta_layer<<<grid1, TPB, 0, stream>>>(y0, base + 3 * layer_stride,
                                              mask + 3 * layer_stride, bd, 3, part);
    reduce_partials<<<grid2, 256, 0, stream>>>(part, out);
}

// Round 9
// 156.087 us; speedup vs baseline: 1.0284x; 1.0284x over previous
//
#include <hip/hip_runtime.h>

// BitDelta chained layers: per layer W = base + bd*mask (4096x4096 fp32),
// x = x @ W, x [16,4096].  Weight-streaming, memory-bound (~150 MB/layer).
//
// R9 = R7 structure with DRAM-friendly address ORDER:
//  - waves interleave k at stride 1: at step j the block's 4 waves read 8
//    CONSECUTIVE rows (16 cchunk-blocks cover the full 16 KB row width ->
//    128 KB dense runs per stream);
//  - per-kchunk phase rotation pj=(j+3*kchunk)&7 decorrelates which run
//    each kchunk-group touches at a given instant (channel spread).
// Same math, same VGPR budget, same grid as R7 (1024 blocks, 4/CU).
//
// Stage 2: 64-block kernel folds the 64 k-partials into the output.

#define DD 4096
#define BB 16
#define KW 16                  // k-rows per wave (8 pairs)
#define NW 4                   // waves per block
#define KC (KW * NW)           // 64 k-rows per block
#define VEC 4
#define CT 256                 // cols per block (64 lanes * 4)
#define TPB 256
#define KCHUNKS (DD / KC)      // 64
#define NCHUNKS (DD / CT)      // 16
#define OUT_ELEMS (BB * DD)    // 65536

__global__ __launch_bounds__(TPB)
void bitdelta_layer(const float* __restrict__ x,
                    const float* __restrict__ base,
                    const float* __restrict__ mask,
                    const float* __restrict__ bitdelta,
                    int layer,
                    float* __restrict__ part) {
    __shared__ float red[16][3 * 64];   // 12 KB reduce buffer

    const int tid = threadIdx.x;
    const int l   = tid & 63;
    const int wid = __builtin_amdgcn_readfirstlane(tid >> 6);  // wave-uniform

    const int bid    = blockIdx.x;
    const int cchunk = bid & (NCHUNKS - 1);
    const int kchunk = bid >> 4;              // bid / NCHUNKS

    const int c0 = cchunk * CT + l * VEC;
    const int k0 = kchunk * KC;               // wave-uniform
    const int ph = (kchunk * 3) & 7;          // phase rotation per kchunk

    const float bd = bitdelta[layer];

    // Wave wid's pair for step j sits at rows k0 + 8*((j+ph)&7) + 2*wid +{0,1}.
    const float* wb = base + (size_t)(k0 + 2 * wid) * DD + c0;
    const float* wm = mask + (size_t)(k0 + 2 * wid) * DD + c0;
    const float* xp = x + k0 + 2 * wid;       // wave-uniform base

    float acc[BB][VEC];
#pragma unroll
    for (int r = 0; r < BB; ++r)
#pragma unroll
        for (int c = 0; c < VEC; ++c) acc[r][c] = 0.0f;

    // Depth-1 window prefetch over the 8 phase-rotated pairs.
    int rowoff = 8 * ph;                      // row offset of pair j=0
    float4 b0 = *reinterpret_cast<const float4*>(wb + (size_t)rowoff * DD);
    float4 b1 = *reinterpret_cast<const float4*>(wb + (size_t)(rowoff + 1) * DD);
    float4 m0 = *reinterpret_cast<const float4*>(wm + (size_t)rowoff * DD);
    float4 m1 = *reinterpret_cast<const float4*>(wm + (size_t)(rowoff + 1) * DD);

#pragma unroll
    for (int j = 0; j < 8; ++j) {
        const int cur = rowoff;               // rows for this step
        float4 nb0, nb1, nm0, nm1;
        if (j + 1 < 8) {
            const int nxt = 8 * ((j + 1 + ph) & 7);
            const float* pb = wb + (size_t)nxt * DD;
            const float* pm = wm + (size_t)nxt * DD;
            nb0 = *reinterpret_cast<const float4*>(pb);
            nb1 = *reinterpret_cast<const float4*>(pb + DD);
            nm0 = *reinterpret_cast<const float4*>(pm);
            nm1 = *reinterpret_cast<const float4*>(pm + DD);
            rowoff = nxt;
        }

        const float w00 = fmaf(bd, m0.x, b0.x);
        const float w01 = fmaf(bd, m0.y, b0.y);
        const float w02 = fmaf(bd, m0.z, b0.z);
        const float w03 = fmaf(bd, m0.w, b0.w);
        const float w10 = fmaf(bd, m1.x, b1.x);
        const float w11 = fmaf(bd, m1.y, b1.y);
        const float w12 = fmaf(bd, m1.z, b1.z);
        const float w13 = fmaf(bd, m1.w, b1.w);

#pragma unroll
        for (int r = 0; r < BB; ++r) {
            // Wave-uniform -> scalar loads on the SMEM pipe.
            const float xv0 = xp[r * DD + cur];
            const float xv1 = xp[r * DD + cur + 1];
            acc[r][0] = fmaf(xv0, w00, acc[r][0]);
            acc[r][1] = fmaf(xv0, w01, acc[r][1]);
            acc[r][2] = fmaf(xv0, w02, acc[r][2]);
            acc[r][3] = fmaf(xv0, w03, acc[r][3]);
            acc[r][0] = fmaf(xv1, w10, acc[r][0]);
            acc[r][1] = fmaf(xv1, w11, acc[r][1]);
            acc[r][2] = fmaf(xv1, w12, acc[r][2]);
            acc[r][3] = fmaf(xv1, w13, acc[r][3]);
        }

        if (j + 1 < 8) { b0 = nb0; b1 = nb1; m0 = nm0; m1 = nm1; }
    }

    // 4-wave LDS reduce, four rounds of 16 elements (12 KB, conflict-free).
#pragma unroll
    for (int t = 0; t < 4; ++t) {
        if (t) __syncthreads();
        if (wid != 0) {
#pragma unroll
            for (int e = 0; e < 16; ++e) {
                const int r = t * 4 + (e >> 2), c = e & 3;
                red[e][(wid - 1) * 64 + l] = acc[r][c];
            }
        }
        __syncthreads();
        if (wid == 0) {
#pragma unroll
            for (int e = 0; e < 16; ++e) {
                const int r = t * 4 + (e >> 2), c = e & 3;
                acc[r][c] += red[e][l] + red[e][64 + l] + red[e][128 + l];
            }
        }
    }

    // Wave 0 writes the block partial: [16][256] slab, float4 stores.
    if (wid == 0) {
        float* pp = part + (size_t)kchunk * OUT_ELEMS;
#pragma unroll
        for (int r = 0; r < BB; ++r) {
            const float4 v = make_float4(acc[r][0], acc[r][1], acc[r][2], acc[r][3]);
            *reinterpret_cast<float4*>(&pp[r * DD + c0]) = v;
        }
    }
}

// Stage 2: out[e] = sum_k part[k][e].  64 blocks x 256 threads x float4.
__global__ __launch_bounds__(256)
void reduce_partials(const float* __restrict__ part, float* __restrict__ out) {
    const int idx = (blockIdx.x * 256 + threadIdx.x) * 4;
    float4 a = *reinterpret_cast<const float4*>(&part[idx]);
#pragma unroll
    for (int k = 1; k < KCHUNKS; ++k) {
        const float4 p = *reinterpret_cast<const float4*>(
            &part[(size_t)k * OUT_ELEMS + idx]);
        a.x += p.x; a.y += p.y; a.z += p.z; a.w += p.w;
    }
    *reinterpret_cast<float4*>(&out[idx]) = a;
}

extern "C" void kernel_launch(void* const* d_in, const int* in_sizes, int n_in,
                              void* d_out, int out_size, void* d_ws, size_t ws_size,
                              hipStream_t stream) {
    const float* x    = (const float*)d_in[0];   // [16,4096]
    const float* base = (const float*)d_in[1];   // [4,4096,4096]
    const float* mask = (const float*)d_in[2];   // [4,4096,4096]
    const float* bd   = (const float*)d_in[3];   // [4]
    float* out = (float*)d_out;                  // [16,4096] fp32

    float* part = (float*)d_ws;                  // 64 x 65536 floats = 16 MB
    float* y0   = part + (size_t)KCHUNKS * OUT_ELEMS;
    float* y1   = y0 + OUT_ELEMS;

    const size_t layer_stride = (size_t)DD * DD;
    const int    grid1 = KCHUNKS * NCHUNKS;      // 1024
    const int    grid2 = OUT_ELEMS / (256 * 4);  // 64

    bitdelta_layer<<<grid1, TPB, 0, stream>>>(x, base, mask, bd, 0, part);
    reduce_partials<<<grid2, 256, 0, stream>>>(part, y0);

    bitdelta_layer<<<grid1, TPB, 0, stream>>>(y0, base + 1 * layer_stride,
                                              mask + 1 * layer_stride, bd, 1, part);
    reduce_partials<<<grid2, 256, 0, stream>>>(part, y1);

    bitdelta_layer<<<grid1, TPB, 0, stream>>>(y1, base + 2 * layer_stride,
                                              mask + 2 * layer_stride, bd, 2, part);
    reduce_partials<<<grid2, 256, 0, stream>>>(part, y0);

    bitdelta_layer<<<grid1, TPB, 0, stream>>>(y0, base + 3 * layer_stride,
                                              mask + 3 * layer_stride, bd, 3, part);
    reduce_partials<<<grid2, 256, 0, stream>>>(part, out);
}

// Round 10
// 140.287 us; speedup vs baseline: 1.1442x; 1.1126x over previous
//
#include <hip/hip_runtime.h>

// BitDelta chained layers: per layer W = base + bd*mask (4096x4096 fp32),
// x = x @ W, x [16,4096].  Weight-streaming, memory-bound (~150 MB/layer).
//
// Stage 1 (per layer): EXACT R7 structure (best: 152.5 us).  grid 1024 =
// (KCHUNKS=64) x (NCHUNKS=16), TPB=256 (4 waves) -> 4 blocks/CU.  Wave owns
// KW=16 k-rows; lane owns VEC=4 cols (float4 = 1 KB granule).  Depth-1
// window prefetch; x via wave-uniform scalar loads; 4-wave LDS reduce;
// wave 0 writes block partial (no atomics).
//
// Stage 2 REWORKED: the old 64-block reduce used 25% of CUs and cost
// ~11 us/layer (~44 us total -- the hidden third of runtime).  Now
// 256 blocks x 64 threads: 1 wave per CU, lane owns one float4 (64
// consecutive f4 per wave = 1 KB contiguous per slab-load), 64 independent
// slab loads per thread = deep ILP.  Expected ~3 us per reduce.

#define DD 4096
#define BB 16
#define KW 16                  // k-rows per wave
#define NW 4                   // waves per block
#define KC (KW * NW)           // 64 k-rows per block
#define VEC 4
#define CT 256                 // cols per block (64 lanes * 4)
#define TPB 256
#define KCHUNKS (DD / KC)      // 64
#define NCHUNKS (DD / CT)      // 16
#define OUT_ELEMS (BB * DD)    // 65536

typedef float f32x4 __attribute__((ext_vector_type(4)));

__global__ __launch_bounds__(TPB)
void bitdelta_layer(const float* __restrict__ x,
                    const float* __restrict__ base,
                    const float* __restrict__ mask,
                    const float* __restrict__ bitdelta,
                    int layer,
                    float* __restrict__ part) {
    __shared__ float red[16][3 * 64];   // 12 KB reduce buffer

    const int tid = threadIdx.x;
    const int l   = tid & 63;
    const int wid = __builtin_amdgcn_readfirstlane(tid >> 6);  // wave-uniform

    const int bid    = blockIdx.x;
    const int cchunk = bid & (NCHUNKS - 1);
    const int kchunk = bid >> 4;              // bid / NCHUNKS

    const int c0 = cchunk * CT + l * VEC;
    const int k0 = kchunk * KC + wid * KW;    // wave-uniform

    const float bd = bitdelta[layer];

    const float* wb = base + (size_t)k0 * DD + c0;
    const float* wm = mask + (size_t)k0 * DD + c0;
    const float* xp = x + k0;                 // wave-uniform base

    float acc[BB][VEC];
#pragma unroll
    for (int r = 0; r < BB; ++r)
#pragma unroll
        for (int c = 0; c < VEC; ++c) acc[r][c] = 0.0f;

    // Window 0 (2 k-rows): float4 loads = 1 KB/wave-instruction.
    float4 b0 = *reinterpret_cast<const float4*>(wb);
    float4 b1 = *reinterpret_cast<const float4*>(wb + DD);
    float4 m0 = *reinterpret_cast<const float4*>(wm);
    float4 m1 = *reinterpret_cast<const float4*>(wm + DD);

#pragma unroll
    for (int kw = 0; kw < KW; kw += 2) {
        float4 nb0, nb1, nm0, nm1;
        if (kw + 2 < KW) {   // compile-time after full unroll
            const float* pb = wb + (size_t)(kw + 2) * DD;
            const float* pm = wm + (size_t)(kw + 2) * DD;
            nb0 = *reinterpret_cast<const float4*>(pb);
            nb1 = *reinterpret_cast<const float4*>(pb + DD);
            nm0 = *reinterpret_cast<const float4*>(pm);
            nm1 = *reinterpret_cast<const float4*>(pm + DD);
        }

        const float w00 = fmaf(bd, m0.x, b0.x);
        const float w01 = fmaf(bd, m0.y, b0.y);
        const float w02 = fmaf(bd, m0.z, b0.z);
        const float w03 = fmaf(bd, m0.w, b0.w);
        const float w10 = fmaf(bd, m1.x, b1.x);
        const float w11 = fmaf(bd, m1.y, b1.y);
        const float w12 = fmaf(bd, m1.z, b1.z);
        const float w13 = fmaf(bd, m1.w, b1.w);

#pragma unroll
        for (int r = 0; r < BB; ++r) {
            // Wave-uniform -> scalar loads on the SMEM pipe.
            const float xv0 = xp[r * DD + kw];
            const float xv1 = xp[r * DD + kw + 1];
            acc[r][0] = fmaf(xv0, w00, acc[r][0]);
            acc[r][1] = fmaf(xv0, w01, acc[r][1]);
            acc[r][2] = fmaf(xv0, w02, acc[r][2]);
            acc[r][3] = fmaf(xv0, w03, acc[r][3]);
            acc[r][0] = fmaf(xv1, w10, acc[r][0]);
            acc[r][1] = fmaf(xv1, w11, acc[r][1]);
            acc[r][2] = fmaf(xv1, w12, acc[r][2]);
            acc[r][3] = fmaf(xv1, w13, acc[r][3]);
        }

        if (kw + 2 < KW) { b0 = nb0; b1 = nb1; m0 = nm0; m1 = nm1; }
    }

    // 4-wave LDS reduce, four rounds of 16 elements (12 KB, conflict-free).
#pragma unroll
    for (int t = 0; t < 4; ++t) {
        if (t) __syncthreads();
        if (wid != 0) {
#pragma unroll
            for (int e = 0; e < 16; ++e) {
                const int r = t * 4 + (e >> 2), c = e & 3;
                red[e][(wid - 1) * 64 + l] = acc[r][c];
            }
        }
        __syncthreads();
        if (wid == 0) {
#pragma unroll
            for (int e = 0; e < 16; ++e) {
                const int r = t * 4 + (e >> 2), c = e & 3;
                acc[r][c] += red[e][l] + red[e][64 + l] + red[e][128 + l];
            }
        }
    }

    // Wave 0 writes the block partial: [16][256] slab, float4 stores.
    if (wid == 0) {
        float* pp = part + (size_t)kchunk * OUT_ELEMS;
#pragma unroll
        for (int r = 0; r < BB; ++r) {
            const float4 v = make_float4(acc[r][0], acc[r][1], acc[r][2], acc[r][3]);
            *reinterpret_cast<float4*>(&pp[r * DD + c0]) = v;
        }
    }
}

// Stage 2: out[e] = sum_k part[k][e].  256 blocks x 64 threads: one wave
// per CU; lane owns one float4 (wave reads 1 KB contiguous per slab);
// 64 independent slab loads per thread (deep ILP).
__global__ __launch_bounds__(64)
void reduce_partials(const float* __restrict__ part, float* __restrict__ out) {
    const int idx = (blockIdx.x * 64 + threadIdx.x) * 4;   // float4 base
    f32x4 a = *reinterpret_cast<const f32x4*>(&part[idx]);
#pragma unroll
    for (int k = 1; k < KCHUNKS; ++k) {
        const f32x4 p = *reinterpret_cast<const f32x4*>(
            &part[(size_t)k * OUT_ELEMS + idx]);
        a += p;
    }
    *reinterpret_cast<f32x4*>(&out[idx]) = a;
}

extern "C" void kernel_launch(void* const* d_in, const int* in_sizes, int n_in,
                              void* d_out, int out_size, void* d_ws, size_t ws_size,
                              hipStream_t stream) {
    const float* x    = (const float*)d_in[0];   // [16,4096]
    const float* base = (const float*)d_in[1];   // [4,4096,4096]
    const float* mask = (const float*)d_in[2];   // [4,4096,4096]
    const float* bd   = (const float*)d_in[3];   // [4]
    float* out = (float*)d_out;                  // [16,4096] fp32

    float* part = (float*)d_ws;                  // 64 x 65536 floats = 16 MB
    float* y0   = part + (size_t)KCHUNKS * OUT_ELEMS;
    float* y1   = y0 + OUT_ELEMS;

    const size_t layer_stride = (size_t)DD * DD;
    const int    grid1 = KCHUNKS * NCHUNKS;      // 1024
    const int    grid2 = OUT_ELEMS / (64 * 4);   // 256 blocks, 64 threads

    bitdelta_layer<<<grid1, TPB, 0, stream>>>(x, base, mask, bd, 0, part);
    reduce_partials<<<grid2, 64, 0, stream>>>(part, y0);

    bitdelta_layer<<<grid1, TPB, 0, stream>>>(y0, base + 1 * layer_stride,
                                              mask + 1 * layer_stride, bd, 1, part);
    reduce_partials<<<grid2, 64, 0, stream>>>(part, y1);

    bitdelta_layer<<<grid1, TPB, 0, stream>>>(y1, base + 2 * layer_stride,
                                              mask + 2 * layer_stride, bd, 2, part);
    reduce_partials<<<grid2, 64, 0, stream>>>(part, y0);

    bitdelta_layer<<<grid1, TPB, 0, stream>>>(y0, base + 3 * layer_stride,
                                              mask + 3 * layer_stride, bd, 3, part);
    reduce_partials<<<grid2, 64, 0, stream>>>(part, out);
}